// Round 1
// baseline (100541.248 us; speedup 1.0000x reference)
//
#include <hip/hip_runtime.h>

#define T_STEPS 2048
#define BATCH   32
#define DIM     512
#define HID     512
#define NB      256   // blocks; each owns JB h-columns
#define JB      2     // h-columns per block (HID / NB)
#define ROWS    8     // 4 gates * JB weight rows per block
#define NTHR    256
#define WSTRIDE 1028  // 1024 + 4 pad (keeps float4 alignment: 1028*4 % 16 == 0)

// ws layout: hbuf[2][BATCH][HID] floats, then ctr, rel ints
#define HBUF_BYTES (2 * BATCH * HID * 4)

__global__ __launch_bounds__(NTHR, 1) void lstm_persist(
    const float* __restrict__ x,    // [T, B, D]
    const float* __restrict__ Wih,  // [4H, D]
    const float* __restrict__ Whh,  // [4H, H]
    const float* __restrict__ bih,  // [4H]
    const float* __restrict__ bhh,  // [4H]
    float* __restrict__ out,        // [T,B,H] ++ hT[B,H] ++ cT[B,H]
    float* __restrict__ hbuf,       // [2][B][H]
    int* __restrict__ ctr, int* __restrict__ rel)
{
    __shared__ float Wl[ROWS][WSTRIDE];   // fused [W_ih | W_hh] rows
    __shared__ float gbuf[ROWS][33];      // gate staging (pad 33 vs conflicts)
    __shared__ float bias[ROWS];
    __shared__ float cst[JB * BATCH];     // cell state, index = bb*2+jj (== tid<64)

    const int tid = threadIdx.x;
    const int bj  = blockIdx.x;       // owns columns j = bj*2 + {0,1}
    const int r   = tid & 7;          // row 0..7 (gate = r>>1, jj = r&1)
    const int b   = tid >> 3;         // batch 0..31

    // ---- one-time: load this block's 8 fused weight rows into LDS ----
    for (int i = tid; i < ROWS * 256; i += NTHR) {   // 2048 float4 slots
        int row = i >> 8;
        int q   = i & 255;                           // quad index 0..255
        int R   = ((row >> 1) << 9) + (bj << 1) + (row & 1);  // gate*512 + j
        float4 v;
        if (q < 128) v = ((const float4*)(Wih + (size_t)R * DIM))[q];
        else         v = ((const float4*)(Whh + (size_t)R * HID))[q - 128];
        *(float4*)&Wl[row][q * 4] = v;
    }
    if (tid < ROWS) {
        int R = ((tid >> 1) << 9) + (bj << 1) + (tid & 1);
        bias[tid] = bih[R] + bhh[R];
    }
    if (tid < JB * BATCH) cst[tid] = 0.f;
    __syncthreads();

    for (int t = 0; t < T_STEPS; ++t) {
        const float4* x4 = (const float4*)(x + ((size_t)t * BATCH + b) * DIM);
        const float4* h4 = (const float4*)(hbuf + (size_t)(t & 1) * BATCH * HID + b * HID);
        const float4* wx = (const float4*)&Wl[r][0];
        const float4* wh = (const float4*)&Wl[r][512];

        float a0 = 0.f, a1 = 0.f, a2 = 0.f, a3 = 0.f;
#pragma unroll 8
        for (int k = 0; k < DIM / 4; ++k) {
            float4 w = wx[k], v = x4[k];
            a0 = fmaf(w.x, v.x, a0); a1 = fmaf(w.y, v.y, a1);
            a2 = fmaf(w.z, v.z, a2); a3 = fmaf(w.w, v.w, a3);
        }
#pragma unroll 8
        for (int k = 0; k < HID / 4; ++k) {
            float4 w = wh[k], v = h4[k];
            a0 = fmaf(w.x, v.x, a0); a1 = fmaf(w.y, v.y, a1);
            a2 = fmaf(w.z, v.z, a2); a3 = fmaf(w.w, v.w, a3);
        }
        gbuf[r][b] = (a0 + a1) + (a2 + a3) + bias[r];
        __syncthreads();

        if (tid < JB * BATCH) {
            int jj = tid & 1, bb = tid >> 1;
            float gi = gbuf[0 + jj][bb];
            float gf = gbuf[2 + jj][bb];
            float gg = gbuf[4 + jj][bb];
            float go = gbuf[6 + jj][bb];
            float ig = 1.f / (1.f + __expf(-gi));
            float fg = 1.f / (1.f + __expf(-gf));
            float g  = tanhf(gg);
            float og = 1.f / (1.f + __expf(-go));
            float c  = fg * cst[tid] + ig * g;
            cst[tid] = c;
            float h  = og * tanhf(c);
            int j = (bj << 1) + jj;
            hbuf[(size_t)((t + 1) & 1) * BATCH * HID + (size_t)bb * HID + j] = h;
            out[((size_t)t * BATCH + bb) * HID + j] = h;
            if (t == T_STEPS - 1) {
                out[(size_t)T_STEPS * BATCH * HID + (size_t)bb * HID + j] = h;
                out[(size_t)T_STEPS * BATCH * HID + (size_t)BATCH * HID + (size_t)bb * HID + j] = c;
            }
        }

        // ---- grid-wide barrier (all NB blocks are co-resident: 1 block/CU) ----
        __threadfence();
        __syncthreads();
        if (tid == 0) {
            int v = __hip_atomic_fetch_add(ctr, 1, __ATOMIC_ACQ_REL, __HIP_MEMORY_SCOPE_AGENT);
            if (v == NB - 1) {
                __hip_atomic_store(ctr, 0, __ATOMIC_RELAXED, __HIP_MEMORY_SCOPE_AGENT);
                __hip_atomic_fetch_add(rel, 1, __ATOMIC_RELEASE, __HIP_MEMORY_SCOPE_AGENT);
            } else {
                while (__hip_atomic_load(rel, __ATOMIC_ACQUIRE, __HIP_MEMORY_SCOPE_AGENT) <= t) {
                    __builtin_amdgcn_s_sleep(1);
                }
            }
        }
        __syncthreads();
    }
}

extern "C" void kernel_launch(void* const* d_in, const int* in_sizes, int n_in,
                              void* d_out, int out_size, void* d_ws, size_t ws_size,
                              hipStream_t stream) {
    (void)in_sizes; (void)n_in; (void)out_size; (void)ws_size;
    const float* x   = (const float*)d_in[0];
    const float* Wih = (const float*)d_in[1];
    const float* Whh = (const float*)d_in[2];
    const float* bih = (const float*)d_in[3];
    const float* bhh = (const float*)d_in[4];
    float* outp = (float*)d_out;
    float* hbuf = (float*)d_ws;
    int*   ctr  = (int*)((char*)d_ws + HBUF_BYTES);
    int*   rel  = ctr + 1;

    // zero h0 state and barrier counters every call (harness does not re-poison)
    hipMemsetAsync(d_ws, 0, HBUF_BYTES + 2 * sizeof(int), stream);
    lstm_persist<<<NB, NTHR, 0, stream>>>(x, Wih, Whh, bih, bhh, outp, hbuf, ctr, rel);
}